// Round 2
// 399.738 us; speedup vs baseline: 1.0874x; 1.0874x over previous
//
#include <hip/hip_runtime.h>
#include <hip/hip_bf16.h>

typedef __bf16 bf16_t;
typedef __bf16 bf16x8 __attribute__((ext_vector_type(8)));
typedef float f32x4 __attribute__((ext_vector_type(4)));

#define NN 8192
#define EE 262144
#define NF 1024
#define NH 512
#define ZD 32

// ---------------- f32 -> bf16 bulk convert (8 elems/thread) ----------------
__global__ __launch_bounds__(256) void k_cvt(const float* __restrict__ in,
                                             bf16_t* __restrict__ out, int n8) {
  int i = blockIdx.x * 256 + threadIdx.x;
  if (i >= n8) return;
  const float4 a = ((const float4*)in)[i * 2];
  const float4 b = ((const float4*)in)[i * 2 + 1];
  bf16x8 o;
  o[0] = (bf16_t)a.x; o[1] = (bf16_t)a.y; o[2] = (bf16_t)a.z; o[3] = (bf16_t)a.w;
  o[4] = (bf16_t)b.x; o[5] = (bf16_t)b.y; o[6] = (bf16_t)b.z; o[7] = (bf16_t)b.w;
  ((bf16x8*)out)[i] = o;
}

// ---------------- transpose + convert: f32 [R,C] -> bf16 [C,R] ----------------
__global__ __launch_bounds__(256) void k_transpose_cvt(const float* __restrict__ in,
                                                       bf16_t* __restrict__ out,
                                                       int R, int C) {
  __shared__ float tile[32][33];
  const int c0 = blockIdx.x * 32, r0 = blockIdx.y * 32;
  const int tx = threadIdx.x & 31, ty = threadIdx.x >> 5;
  #pragma unroll
  for (int i = ty; i < 32; i += 8)
    tile[i][tx] = in[(size_t)(r0 + i) * C + (c0 + tx)];
  __syncthreads();
  #pragma unroll
  for (int i = ty; i < 32; i += 8)
    out[(size_t)(c0 + i) * R + (r0 + tx)] = (bf16_t)tile[tx][i];
}

// ---------------- W1|W2 transpose+convert in one launch: [NH,ZD]x2 -> bf16 [64,NH] ----------------
__global__ __launch_bounds__(256) void k_transpose_w12(const float* __restrict__ W1,
                                                       const float* __restrict__ W2,
                                                       bf16_t* __restrict__ out) {
  __shared__ float tile[32][33];
  const float* in = blockIdx.z ? W2 : W1;
  bf16_t* o = out + (size_t)blockIdx.z * ZD * NH;
  const int r0 = blockIdx.y * 32;
  const int tx = threadIdx.x & 31, ty = threadIdx.x >> 5;
  #pragma unroll
  for (int i = ty; i < 32; i += 8)
    tile[i][tx] = in[(size_t)(r0 + i) * ZD + tx];
  __syncthreads();
  #pragma unroll
  for (int i = ty; i < 32; i += 8)
    o[(size_t)(i)*NH + (r0 + tx)] = (bf16_t)tile[tx][i];
}

// ---------------- CSR row_ptr from sorted rows ----------------
__global__ void k_rowptr(const int* __restrict__ rows, int* __restrict__ rp,
                         int n, int e) {
  int r = blockIdx.x * 256 + threadIdx.x;
  if (r > n) return;
  if (r == n) { rp[n] = e; return; }
  int lo = 0, hi = e;
  while (lo < hi) { int mid = (lo + hi) >> 1; if (rows[mid] < r) lo = mid + 1; else hi = mid; }
  rp[r] = lo;
}

// ---------------- GEMM1: XW0b[M,N] bf16 = A[M,K] bf16 @ Bt[N,K]^T, 128x128 tile ----------------
__global__ __launch_bounds__(256) void k_gemm_bt_128x128(
    const bf16_t* __restrict__ A, const bf16_t* __restrict__ Bt,
    bf16_t* __restrict__ C, int M, int N, int K) {
  __shared__ bf16_t As[128 * 32];
  __shared__ bf16_t Bs[128 * 32];
  const int tid = threadIdx.x;
  const int lane = tid & 63, wave = tid >> 6;
  const int wx = wave & 1, wy = wave >> 1;
  const int m0 = blockIdx.y * 128, n0 = blockIdx.x * 128;
  const int q = lane >> 4, ml = lane & 15;

  const int sr = tid >> 2, ss = tid & 3;
  const int sw_lo = sr * 32 + ((ss ^ (sr & 3)) * 8);
  const int sw_hi = sw_lo + 64 * 32;

  int a_off[4], b_off[4];
  #pragma unroll
  for (int i = 0; i < 4; ++i) {
    int m = wy * 64 + i * 16 + ml;
    a_off[i] = m * 32 + ((q ^ (m & 3)) * 8);
    int n = wx * 64 + i * 16 + ml;
    b_off[i] = n * 32 + ((q ^ (n & 3)) * 8);
  }

  f32x4 acc[4][4];
  #pragma unroll
  for (int i = 0; i < 4; ++i)
    #pragma unroll
    for (int j = 0; j < 4; ++j)
      acc[i][j] = (f32x4){0.f, 0.f, 0.f, 0.f};

  const bf16_t* ga = A + (size_t)(m0 + sr) * K + ss * 8;
  const bf16_t* gb = Bt + (size_t)(n0 + sr) * K + ss * 8;
  const size_t stride64 = (size_t)64 * K;

  for (int k0 = 0; k0 < K; k0 += 32) {
    int4 va0 = *(const int4*)(ga + k0);
    int4 va1 = *(const int4*)(ga + stride64 + k0);
    int4 vb0 = *(const int4*)(gb + k0);
    int4 vb1 = *(const int4*)(gb + stride64 + k0);
    __syncthreads();
    *(int4*)(&As[sw_lo]) = va0;
    *(int4*)(&As[sw_hi]) = va1;
    *(int4*)(&Bs[sw_lo]) = vb0;
    *(int4*)(&Bs[sw_hi]) = vb1;
    __syncthreads();
    bf16x8 af[4], bfr[4];
    #pragma unroll
    for (int i = 0; i < 4; ++i) af[i] = *(const bf16x8*)(&As[a_off[i]]);
    #pragma unroll
    for (int j = 0; j < 4; ++j) bfr[j] = *(const bf16x8*)(&Bs[b_off[j]]);
    #pragma unroll
    for (int i = 0; i < 4; ++i)
      #pragma unroll
      for (int j = 0; j < 4; ++j)
        acc[i][j] = __builtin_amdgcn_mfma_f32_16x16x32_bf16(af[i], bfr[j], acc[i][j], 0, 0, 0);
  }

  #pragma unroll
  for (int i = 0; i < 4; ++i) {
    const int row = m0 + wy * 64 + i * 16 + q * 4;
    #pragma unroll
    for (int j = 0; j < 4; ++j) {
      const int col = n0 + wx * 64 + j * 16 + ml;
      #pragma unroll
      for (int r = 0; r < 4; ++r)
        C[(size_t)(row + r) * N + col] = (bf16_t)acc[i][j][r];
    }
  }
}

// ---------------- GEMM2: HW f32 = h bf16 @ Wct^T, 128x64 tile ----------------
__global__ __launch_bounds__(256) void k_gemm_bt_128x64(
    const bf16_t* __restrict__ A, const bf16_t* __restrict__ Bt,
    float* __restrict__ C, int M, int N, int K) {
  __shared__ bf16_t As[128 * 32];
  __shared__ bf16_t Bs[64 * 32];
  const int tid = threadIdx.x;
  const int lane = tid & 63, wave = tid >> 6;
  const int m0 = blockIdx.y * 128;
  const int q = lane >> 4, ml = lane & 15;
  const int sr = tid >> 2, ss = tid & 3;
  const int sw_lo = sr * 32 + ((ss ^ (sr & 3)) * 8);
  const int sw_hi = sw_lo + 64 * 32;

  int a_off[2], b_off[4];
  #pragma unroll
  for (int i = 0; i < 2; ++i) {
    int m = wave * 32 + i * 16 + ml;
    a_off[i] = m * 32 + ((q ^ (m & 3)) * 8);
  }
  #pragma unroll
  for (int j = 0; j < 4; ++j) {
    int n = j * 16 + ml;
    b_off[j] = n * 32 + ((q ^ (n & 3)) * 8);
  }

  f32x4 acc[2][4];
  #pragma unroll
  for (int i = 0; i < 2; ++i)
    #pragma unroll
    for (int j = 0; j < 4; ++j)
      acc[i][j] = (f32x4){0.f, 0.f, 0.f, 0.f};

  const bf16_t* ga = A + (size_t)(m0 + sr) * K + ss * 8;
  const bf16_t* gb = Bt + (size_t)sr * K + ss * 8;
  const size_t stride64 = (size_t)64 * K;

  for (int k0 = 0; k0 < K; k0 += 32) {
    int4 va0 = *(const int4*)(ga + k0);
    int4 va1 = *(const int4*)(ga + stride64 + k0);
    int4 vb0 = *(const int4*)(gb + k0);
    __syncthreads();
    *(int4*)(&As[sw_lo]) = va0;
    *(int4*)(&As[sw_hi]) = va1;
    *(int4*)(&Bs[sw_lo]) = vb0;
    __syncthreads();
    bf16x8 af[2], bfr[4];
    #pragma unroll
    for (int i = 0; i < 2; ++i) af[i] = *(const bf16x8*)(&As[a_off[i]]);
    #pragma unroll
    for (int j = 0; j < 4; ++j) bfr[j] = *(const bf16x8*)(&Bs[b_off[j]]);
    #pragma unroll
    for (int i = 0; i < 2; ++i)
      #pragma unroll
      for (int j = 0; j < 4; ++j)
        acc[i][j] = __builtin_amdgcn_mfma_f32_16x16x32_bf16(af[i], bfr[j], acc[i][j], 0, 0, 0);
  }

  #pragma unroll
  for (int i = 0; i < 2; ++i) {
    const int row = m0 + wave * 32 + i * 16 + q * 4;
    #pragma unroll
    for (int j = 0; j < 4; ++j) {
      const int col = j * 16 + ml;
      #pragma unroll
      for (int r = 0; r < 4; ++r)
        C[(size_t)(row + r) * N + col] = acc[i][j][r];
    }
  }
}

// ---------------- SpMM layer1: 256-thread blocks, 4 waves = 4 rows, one chunk/block ----------------
// blockIdx.x = rowGroup*4 + chunk; chunk correlates with XCD via round-robin
// dispatch (blockIdx%8 in {chunk, chunk+4}) -> each XCD's L2 holds one 2MB chunk.
// XW0b packed as bf16x2 (uint) [NN][256]; lane t handles pair chunk*64+t.
__global__ __launch_bounds__(256) void k_spmm_h(
    const int* __restrict__ rp, const int* __restrict__ cols,
    const float* __restrict__ vals, const unsigned int* __restrict__ XW0b,
    const float* __restrict__ b0, bf16_t* __restrict__ h) {
  const int chunk = blockIdx.x & 3;
  const int row = (blockIdx.x >> 2) * 4 + (threadIdx.x >> 6);
  const int t = threadIdx.x & 63;
  const unsigned int* tab = XW0b + chunk * 64 + t;
  int e = rp[row];
  const int end = rp[row + 1];
  float a0 = 0.f, a1 = 0.f;
  for (; e + 3 < end; e += 4) {
    const int c0 = cols[e], c1 = cols[e + 1], c2 = cols[e + 2], c3 = cols[e + 3];
    const float v0 = vals[e], v1 = vals[e + 1], v2 = vals[e + 2], v3 = vals[e + 3];
    const unsigned int p0 = tab[(size_t)c0 * 256];
    const unsigned int p1 = tab[(size_t)c1 * 256];
    const unsigned int p2 = tab[(size_t)c2 * 256];
    const unsigned int p3 = tab[(size_t)c3 * 256];
    a0 += v0 * __uint_as_float(p0 << 16);
    a1 += v0 * __uint_as_float(p0 & 0xffff0000u);
    a0 += v1 * __uint_as_float(p1 << 16);
    a1 += v1 * __uint_as_float(p1 & 0xffff0000u);
    a0 += v2 * __uint_as_float(p2 << 16);
    a1 += v2 * __uint_as_float(p2 & 0xffff0000u);
    a0 += v3 * __uint_as_float(p3 << 16);
    a1 += v3 * __uint_as_float(p3 & 0xffff0000u);
  }
  for (; e < end; ++e) {
    const float v0 = vals[e];
    const unsigned int p0 = tab[(size_t)cols[e] * 256];
    a0 += v0 * __uint_as_float(p0 << 16);
    a1 += v0 * __uint_as_float(p0 & 0xffff0000u);
  }
  const int d = chunk * 128 + t * 2;
  a0 += b0[d];
  a1 += b0[d + 1];
  bf16_t x0 = (bf16_t)fmaxf(a0, 0.f);
  bf16_t x1 = (bf16_t)fmaxf(a1, 0.f);
  const unsigned int pk = (unsigned int)(*(const unsigned short*)&x0) |
                          ((unsigned int)(*(const unsigned short*)&x1) << 16);
  *(unsigned int*)(h + (size_t)row * NH + d) = pk;
}

// ---------------- SpMM D=64: 256-thread blocks, 4 waves = 4 rows ----------------
__global__ __launch_bounds__(256) void k_spmm_z(
    const int* __restrict__ rp, const int* __restrict__ cols,
    const float* __restrict__ vals, const float* __restrict__ HW,
    const float* __restrict__ b1, const float* __restrict__ b2,
    float* __restrict__ out_z, float* __restrict__ out_mu,
    float* __restrict__ out_lv, bf16_t* __restrict__ zb) {
  const int r = blockIdx.x * 4 + (threadIdx.x >> 6);
  const int t = threadIdx.x & 63;
  int e = rp[r];
  const int end = rp[r + 1];
  float acc = 0.f;
  for (; e + 3 < end; e += 4) {
    const float v0 = vals[e], v1 = vals[e + 1], v2 = vals[e + 2], v3 = vals[e + 3];
    const float s0 = HW[(size_t)cols[e] * 64 + t];
    const float s1 = HW[(size_t)cols[e + 1] * 64 + t];
    const float s2 = HW[(size_t)cols[e + 2] * 64 + t];
    const float s3 = HW[(size_t)cols[e + 3] * 64 + t];
    acc += v0 * s0;
    acc += v1 * s1;
    acc += v2 * s2;
    acc += v3 * s3;
  }
  for (; e < end; ++e) acc += vals[e] * HW[(size_t)cols[e] * 64 + t];
  const float b = (t < ZD) ? b1[t] : b2[t - ZD];
  const float v = fmaxf(acc + b, 0.f);
  if (t < ZD) {
    out_mu[(size_t)r * ZD + t] = v;
    out_z[(size_t)r * ZD + t] = v;
    zb[(size_t)r * ZD + t] = (bf16_t)v;
  } else {
    out_lv[(size_t)r * ZD + (t - ZD)] = v;
  }
}

// ---------------- decoder: out = sigmoid(Z @ Z^T) f32 ----------------
// Epilogue restructured: sigmoid in-reg, LDS transpose (64x132 padded, 2 half-passes),
// then contiguous f32x4 nontemporal streaming stores (16 B/lane, 512 B/row-group)
// instead of 64 scattered dword stores per thread.
__global__ __launch_bounds__(256) void k_decoder(const bf16_t* __restrict__ Z,
                                                 float* __restrict__ out) {
  __shared__ bf16_t Zr[128 * 32];
  __shared__ bf16_t Zc[128 * 32];
  __shared__ float tile[64][132];  // +4 pad: <=2-way bank alias on writes (free)
  const int tid = threadIdx.x;
  const int lane = tid & 63, wave = tid >> 6;
  const int wx = wave & 1, wy = wave >> 1;
  const int m0 = blockIdx.y * 128, n0 = blockIdx.x * 128;
  const int q = lane >> 4, ml = lane & 15;
  const int sr = tid >> 2, ss = tid & 3;
  const int sw_lo = sr * 32 + ((ss ^ (sr & 3)) * 8);
  const int sw_hi = sw_lo + 64 * 32;

  *(int4*)(&Zr[sw_lo]) = *((const int4*)(Z + (size_t)(m0 + sr) * ZD) + ss);
  *(int4*)(&Zr[sw_hi]) = *((const int4*)(Z + (size_t)(m0 + sr + 64) * ZD) + ss);
  *(int4*)(&Zc[sw_lo]) = *((const int4*)(Z + (size_t)(n0 + sr) * ZD) + ss);
  *(int4*)(&Zc[sw_hi]) = *((const int4*)(Z + (size_t)(n0 + sr + 64) * ZD) + ss);
  __syncthreads();

  bf16x8 af[4], bfr[4];
  #pragma unroll
  for (int i = 0; i < 4; ++i) {
    int m = wy * 64 + i * 16 + ml;
    af[i] = *(const bf16x8*)(&Zr[m * 32 + ((q ^ (m & 3)) * 8)]);
    int n = wx * 64 + i * 16 + ml;
    bfr[i] = *(const bf16x8*)(&Zc[n * 32 + ((q ^ (n & 3)) * 8)]);
  }

  f32x4 acc[4][4];
  const f32x4 zero = (f32x4){0.f, 0.f, 0.f, 0.f};
  #pragma unroll
  for (int i = 0; i < 4; ++i)
    #pragma unroll
    for (int j = 0; j < 4; ++j)
      acc[i][j] = __builtin_amdgcn_mfma_f32_16x16x32_bf16(af[i], bfr[j], zero, 0, 0, 0);

  // sigmoid in registers
  #pragma unroll
  for (int i = 0; i < 4; ++i)
    #pragma unroll
    for (int j = 0; j < 4; ++j)
      #pragma unroll
      for (int r = 0; r < 4; ++r)
        acc[i][j][r] = 1.f / (1.f + __expf(-acc[i][j][r]));

  const int g = tid >> 5, c4 = tid & 31;
  #pragma unroll
  for (int half = 0; half < 2; ++half) {
    if (wy == half) {
      #pragma unroll
      for (int i = 0; i < 4; ++i)
        #pragma unroll
        for (int j = 0; j < 4; ++j)
          #pragma unroll
          for (int r = 0; r < 4; ++r)
            tile[i * 16 + q * 4 + r][wx * 64 + j * 16 + ml] = acc[i][j][r];
    }
    __syncthreads();
    float* orow = out + (size_t)(m0 + half * 64) * NN + n0;
    #pragma unroll
    for (int p = 0; p < 8; ++p) {
      const int lr = p * 8 + g;
      f32x4 v = *(const f32x4*)&tile[lr][c4 * 4];
      __builtin_nontemporal_store(v, (f32x4*)(orow + (size_t)lr * NN + c4 * 4));
    }
    __syncthreads();
  }
}

extern "C" void kernel_launch(void* const* d_in, const int* in_sizes, int n_in,
                              void* d_out, int out_size, void* d_ws, size_t ws_size,
                              hipStream_t stream) {
  const float* x        = (const float*)d_in[0];
  const float* adj_vals = (const float*)d_in[1];
  const float* W0       = (const float*)d_in[2];
  const float* b0       = (const float*)d_in[3];
  const float* W1       = (const float*)d_in[4];
  const float* b1       = (const float*)d_in[5];
  const float* W2       = (const float*)d_in[6];
  const float* b2       = (const float*)d_in[7];
  const int* adj_rows   = (const int*)d_in[8];
  const int* adj_cols   = (const int*)d_in[9];

  char* ws = (char*)d_ws;
  bf16_t* XW0b = (bf16_t*)(ws);                  // 8192*512*2   =  8388608
  float*  HW   = (float*)(ws + 8388608);         // 8192*64*4    =  2097152
  bf16_t* h    = (bf16_t*)(ws + 10485760);       // 8192*512*2   =  8388608
  bf16_t* W0t  = (bf16_t*)(ws + 18874368);       // 512*1024*2   =  1048576
  bf16_t* Wct  = (bf16_t*)(ws + 19922944);       // 64*512*2     =    65536
  bf16_t* xb   = (bf16_t*)(ws + 19988480);       // 8192*1024*2  = 16777216
  bf16_t* zb   = (bf16_t*)(ws + 36765696);       // 8192*32*2    =   524288
  int*    rp   = (int*)(ws + 37289984);          // 8193*4

  float* out     = (float*)d_out;
  float* out_adj = out;
  float* out_z   = out + (size_t)NN * NN;
  float* out_mu  = out_z + (size_t)NN * ZD;
  float* out_lv  = out_mu + (size_t)NN * ZD;

  // prep: convert x to bf16; transpose+convert weights; build CSR row_ptr
  k_cvt<<<(NN * NF / 8 + 255) / 256, 256, 0, stream>>>(x, xb, NN * NF / 8);
  k_transpose_cvt<<<dim3(NH / 32, NF / 32), 256, 0, stream>>>(W0, W0t, NF, NH);
  k_transpose_w12<<<dim3(1, NH / 32, 2), 256, 0, stream>>>(W1, W2, Wct);
  k_rowptr<<<33, 256, 0, stream>>>(adj_rows, rp, NN, EE);

  // layer 1: XW0b = bf16(x @ W0) ; h = relu(spmm(XW0b) + b0)
  k_gemm_bt_128x128<<<dim3(NH / 128, NN / 128), 256, 0, stream>>>(xb, W0t, XW0b, NN, NH, NF);
  k_spmm_h<<<NN, 256, 0, stream>>>(rp, adj_cols, adj_vals,
                                   (const unsigned int*)XW0b, b0, h);

  // layer 2: HW = h @ [W1|W2] ; mu/logvar = relu(spmm(HW) + b)
  k_gemm_bt_128x64<<<dim3(1, NN / 128), 256, 0, stream>>>(h, Wct, HW, NN, 64, NH);
  k_spmm_z<<<NN / 4, 256, 0, stream>>>(rp, adj_cols, adj_vals, HW, b1, b2, out_z, out_mu, out_lv, zb);

  // decoder
  k_decoder<<<dim3(NN / 128, NN / 128), 256, 0, stream>>>(zb, out_adj);
}

// Round 3
// 379.782 us; speedup vs baseline: 1.1445x; 1.0525x over previous
//
#include <hip/hip_runtime.h>
#include <hip/hip_bf16.h>

typedef __bf16 bf16_t;
typedef __bf16 bf16x8 __attribute__((ext_vector_type(8)));
typedef float f32x4 __attribute__((ext_vector_type(4)));

#define NN 8192
#define EE 262144
#define NF 1024
#define NH 512
#define ZD 32

static __device__ __forceinline__ unsigned short bf16_bits(bf16_t v) {
  union { bf16_t b; unsigned short u; } c;
  c.b = v;
  return c.u;
}

// ---------------- fused prep: cvt x | transpose W0 | transpose W1/W2 | rowptr | edge pack ----------------
// block ranges: [0,4096) cvt, [4096,4608) W0^T, [4608,4640) W12^T, [4640,4673) rowptr, [4673,4929) edge pack
__global__ __launch_bounds__(256) void k_prep(
    const float* __restrict__ x, bf16_t* __restrict__ xb,
    const float* __restrict__ W0, bf16_t* __restrict__ W0t,
    const float* __restrict__ W1, const float* __restrict__ W2, bf16_t* __restrict__ Wct,
    const int* __restrict__ rows, int* __restrict__ rp,
    const int* __restrict__ cols, const float* __restrict__ vals, int2* __restrict__ ev) {
  __shared__ float tile[32][33];
  const int b = blockIdx.x;
  const int tid = threadIdx.x;

  if (b < 4096) {
    // cvt x -> bf16, 8 elems/thread (4096*256*8 == NN*NF exactly)
    const int i = b * 256 + tid;
    const float4 a = ((const float4*)x)[i * 2];
    const float4 c = ((const float4*)x)[i * 2 + 1];
    bf16x8 o;
    o[0] = (bf16_t)a.x; o[1] = (bf16_t)a.y; o[2] = (bf16_t)a.z; o[3] = (bf16_t)a.w;
    o[4] = (bf16_t)c.x; o[5] = (bf16_t)c.y; o[6] = (bf16_t)c.z; o[7] = (bf16_t)c.w;
    ((bf16x8*)xb)[i] = o;
  } else if (b < 4608) {
    // W0 [NF,NH] f32 -> W0t [NH,NF] bf16
    const int bx = b - 4096;
    const int c0 = (bx & 15) * 32, r0 = (bx >> 4) * 32;
    const int tx = tid & 31, ty = tid >> 5;
    #pragma unroll
    for (int i = ty; i < 32; i += 8)
      tile[i][tx] = W0[(size_t)(r0 + i) * NH + (c0 + tx)];
    __syncthreads();
    #pragma unroll
    for (int i = ty; i < 32; i += 8)
      W0t[(size_t)(c0 + i) * NF + (r0 + tx)] = (bf16_t)tile[tx][i];
  } else if (b < 4640) {
    // W1|W2 [NH,ZD] f32 -> Wct [64,NH] bf16
    const int idx = b - 4608;
    const int z = idx & 1, y = idx >> 1;
    const float* in = z ? W2 : W1;
    bf16_t* o = Wct + (size_t)z * ZD * NH;
    const int r0 = y * 32;
    const int tx = tid & 31, ty = tid >> 5;
    #pragma unroll
    for (int i = ty; i < 32; i += 8)
      tile[i][tx] = in[(size_t)(r0 + i) * ZD + tx];
    __syncthreads();
    #pragma unroll
    for (int i = ty; i < 32; i += 8)
      o[(size_t)(i)*NH + (r0 + tx)] = (bf16_t)tile[tx][i];
  } else if (b < 4673) {
    // CSR row_ptr via binary search over sorted rows
    const int r = (b - 4640) * 256 + tid;
    if (r > NN) return;
    if (r == NN) { rp[NN] = EE; return; }
    int lo = 0, hi = EE;
    while (lo < hi) { int mid = (lo + hi) >> 1; if (rows[mid] < r) lo = mid + 1; else hi = mid; }
    rp[r] = lo;
  } else {
    // pack (col, val) -> int2, 4 edges/thread (256 blocks * 256 thr * 4 == EE exactly)
    const int i = ((b - 4673) * 256 + tid) * 4;
    const int4 c4 = *(const int4*)(cols + i);
    const float4 v4 = *(const float4*)(vals + i);
    int4* dst = (int4*)(ev + i);
    dst[0] = make_int4(c4.x, __float_as_int(v4.x), c4.y, __float_as_int(v4.y));
    dst[1] = make_int4(c4.z, __float_as_int(v4.z), c4.w, __float_as_int(v4.w));
  }
}

// ---------------- GEMM1: XW0b[M,N] bf16 = A[M,K] bf16 @ Bt[N,K]^T, 128x128 tile ----------------
__global__ __launch_bounds__(256) void k_gemm_bt_128x128(
    const bf16_t* __restrict__ A, const bf16_t* __restrict__ Bt,
    bf16_t* __restrict__ C, int M, int N, int K) {
  __shared__ bf16_t As[128 * 32];
  __shared__ bf16_t Bs[128 * 32];
  const int tid = threadIdx.x;
  const int lane = tid & 63, wave = tid >> 6;
  const int wx = wave & 1, wy = wave >> 1;
  const int m0 = blockIdx.y * 128, n0 = blockIdx.x * 128;
  const int q = lane >> 4, ml = lane & 15;

  const int sr = tid >> 2, ss = tid & 3;
  const int sw_lo = sr * 32 + ((ss ^ (sr & 3)) * 8);
  const int sw_hi = sw_lo + 64 * 32;

  int a_off[4], b_off[4];
  #pragma unroll
  for (int i = 0; i < 4; ++i) {
    int m = wy * 64 + i * 16 + ml;
    a_off[i] = m * 32 + ((q ^ (m & 3)) * 8);
    int n = wx * 64 + i * 16 + ml;
    b_off[i] = n * 32 + ((q ^ (n & 3)) * 8);
  }

  f32x4 acc[4][4];
  #pragma unroll
  for (int i = 0; i < 4; ++i)
    #pragma unroll
    for (int j = 0; j < 4; ++j)
      acc[i][j] = (f32x4){0.f, 0.f, 0.f, 0.f};

  const bf16_t* ga = A + (size_t)(m0 + sr) * K + ss * 8;
  const bf16_t* gb = Bt + (size_t)(n0 + sr) * K + ss * 8;
  const size_t stride64 = (size_t)64 * K;

  for (int k0 = 0; k0 < K; k0 += 32) {
    int4 va0 = *(const int4*)(ga + k0);
    int4 va1 = *(const int4*)(ga + stride64 + k0);
    int4 vb0 = *(const int4*)(gb + k0);
    int4 vb1 = *(const int4*)(gb + stride64 + k0);
    __syncthreads();
    *(int4*)(&As[sw_lo]) = va0;
    *(int4*)(&As[sw_hi]) = va1;
    *(int4*)(&Bs[sw_lo]) = vb0;
    *(int4*)(&Bs[sw_hi]) = vb1;
    __syncthreads();
    bf16x8 af[4], bfr[4];
    #pragma unroll
    for (int i = 0; i < 4; ++i) af[i] = *(const bf16x8*)(&As[a_off[i]]);
    #pragma unroll
    for (int j = 0; j < 4; ++j) bfr[j] = *(const bf16x8*)(&Bs[b_off[j]]);
    #pragma unroll
    for (int i = 0; i < 4; ++i)
      #pragma unroll
      for (int j = 0; j < 4; ++j)
        acc[i][j] = __builtin_amdgcn_mfma_f32_16x16x32_bf16(af[i], bfr[j], acc[i][j], 0, 0, 0);
  }

  #pragma unroll
  for (int i = 0; i < 4; ++i) {
    const int row = m0 + wy * 64 + i * 16 + q * 4;
    #pragma unroll
    for (int j = 0; j < 4; ++j) {
      const int col = n0 + wx * 64 + j * 16 + ml;
      #pragma unroll
      for (int r = 0; r < 4; ++r)
        C[(size_t)(row + r) * N + col] = (bf16_t)acc[i][j][r];
    }
  }
}

// ---------------- GEMM2: HW f32 = h bf16 @ Wct^T, 128x64 tile ----------------
__global__ __launch_bounds__(256) void k_gemm_bt_128x64(
    const bf16_t* __restrict__ A, const bf16_t* __restrict__ Bt,
    float* __restrict__ C, int M, int N, int K) {
  __shared__ bf16_t As[128 * 32];
  __shared__ bf16_t Bs[64 * 32];
  const int tid = threadIdx.x;
  const int lane = tid & 63, wave = tid >> 6;
  const int m0 = blockIdx.y * 128;
  const int q = lane >> 4, ml = lane & 15;
  const int sr = tid >> 2, ss = tid & 3;
  const int sw_lo = sr * 32 + ((ss ^ (sr & 3)) * 8);
  const int sw_hi = sw_lo + 64 * 32;

  int a_off[2], b_off[4];
  #pragma unroll
  for (int i = 0; i < 2; ++i) {
    int m = wave * 32 + i * 16 + ml;
    a_off[i] = m * 32 + ((q ^ (m & 3)) * 8);
  }
  #pragma unroll
  for (int j = 0; j < 4; ++j) {
    int n = j * 16 + ml;
    b_off[j] = n * 32 + ((q ^ (n & 3)) * 8);
  }

  f32x4 acc[2][4];
  #pragma unroll
  for (int i = 0; i < 2; ++i)
    #pragma unroll
    for (int j = 0; j < 4; ++j)
      acc[i][j] = (f32x4){0.f, 0.f, 0.f, 0.f};

  const bf16_t* ga = A + (size_t)(m0 + sr) * K + ss * 8;
  const bf16_t* gb = Bt + (size_t)sr * K + ss * 8;
  const size_t stride64 = (size_t)64 * K;

  for (int k0 = 0; k0 < K; k0 += 32) {
    int4 va0 = *(const int4*)(ga + k0);
    int4 va1 = *(const int4*)(ga + stride64 + k0);
    int4 vb0 = *(const int4*)(gb + k0);
    __syncthreads();
    *(int4*)(&As[sw_lo]) = va0;
    *(int4*)(&As[sw_hi]) = va1;
    *(int4*)(&Bs[sw_lo]) = vb0;
    __syncthreads();
    bf16x8 af[2], bfr[4];
    #pragma unroll
    for (int i = 0; i < 2; ++i) af[i] = *(const bf16x8*)(&As[a_off[i]]);
    #pragma unroll
    for (int j = 0; j < 4; ++j) bfr[j] = *(const bf16x8*)(&Bs[b_off[j]]);
    #pragma unroll
    for (int i = 0; i < 2; ++i)
      #pragma unroll
      for (int j = 0; j < 4; ++j)
        acc[i][j] = __builtin_amdgcn_mfma_f32_16x16x32_bf16(af[i], bfr[j], acc[i][j], 0, 0, 0);
  }

  #pragma unroll
  for (int i = 0; i < 2; ++i) {
    const int row = m0 + wave * 32 + i * 16 + q * 4;
    #pragma unroll
    for (int j = 0; j < 4; ++j) {
      const int col = j * 16 + ml;
      #pragma unroll
      for (int r = 0; r < 4; ++r)
        C[(size_t)(row + r) * N + col] = acc[i][j][r];
    }
  }
}

// ---------------- SpMM layer1: 512-thr blocks = 4 rows x 2 chunks; LDS edge staging; uint2 gathers ----------------
// XW0b viewed as uint2 [NN][128]; wave (chunk,row) lane t gathers uint2 at row*128 + chunk*64 + t
// (512B/wave/edge, half the gather instrs of dword). Edges staged once per block into LDS.
__global__ __launch_bounds__(512) void k_spmm_h(
    const int* __restrict__ rp, const int2* __restrict__ ev,
    const uint2* __restrict__ XW0b, const float* __restrict__ b0,
    bf16_t* __restrict__ h) {
  __shared__ int2 se[512];
  const int rg = blockIdx.x;                 // group of 4 rows
  const int tid = threadIdx.x;
  const int wave = tid >> 6, t = tid & 63;
  const int row = rg * 4 + (wave & 3);
  const int chunk = wave >> 2;

  const int base = rp[rg * 4];
  const int cnt = rp[rg * 4 + 4] - base;
  const int scnt = cnt < 512 ? cnt : 512;
  for (int i = tid; i < scnt; i += 512) se[i] = ev[base + i];
  __syncthreads();

  int e = rp[row] - base;
  const int end = rp[row + 1] - base;
  const int se_end = end < 512 ? end : 512;
  const uint2* tab = XW0b + chunk * 64 + t;

  float a0 = 0.f, a1 = 0.f, a2 = 0.f, a3 = 0.f;
  for (; e + 3 < se_end; e += 4) {
    const int2 p0 = se[e], p1 = se[e + 1], p2 = se[e + 2], p3 = se[e + 3];
    const uint2 g0 = tab[(size_t)p0.x * 128];
    const uint2 g1 = tab[(size_t)p1.x * 128];
    const uint2 g2 = tab[(size_t)p2.x * 128];
    const uint2 g3 = tab[(size_t)p3.x * 128];
    const float v0 = __int_as_float(p0.y), v1 = __int_as_float(p1.y);
    const float v2 = __int_as_float(p2.y), v3 = __int_as_float(p3.y);
    a0 += v0 * __uint_as_float(g0.x << 16);
    a1 += v0 * __uint_as_float(g0.x & 0xffff0000u);
    a2 += v0 * __uint_as_float(g0.y << 16);
    a3 += v0 * __uint_as_float(g0.y & 0xffff0000u);
    a0 += v1 * __uint_as_float(g1.x << 16);
    a1 += v1 * __uint_as_float(g1.x & 0xffff0000u);
    a2 += v1 * __uint_as_float(g1.y << 16);
    a3 += v1 * __uint_as_float(g1.y & 0xffff0000u);
    a0 += v2 * __uint_as_float(g2.x << 16);
    a1 += v2 * __uint_as_float(g2.x & 0xffff0000u);
    a2 += v2 * __uint_as_float(g2.y << 16);
    a3 += v2 * __uint_as_float(g2.y & 0xffff0000u);
    a0 += v3 * __uint_as_float(g3.x << 16);
    a1 += v3 * __uint_as_float(g3.x & 0xffff0000u);
    a2 += v3 * __uint_as_float(g3.y << 16);
    a3 += v3 * __uint_as_float(g3.y & 0xffff0000u);
  }
  for (; e < se_end; ++e) {
    const int2 p = se[e];
    const uint2 g = tab[(size_t)p.x * 128];
    const float v = __int_as_float(p.y);
    a0 += v * __uint_as_float(g.x << 16);
    a1 += v * __uint_as_float(g.x & 0xffff0000u);
    a2 += v * __uint_as_float(g.y << 16);
    a3 += v * __uint_as_float(g.y & 0xffff0000u);
  }
  for (; e < end; ++e) {  // spill path if >512 edges in a 4-row group (not expected)
    const int2 p = ev[base + e];
    const uint2 g = tab[(size_t)p.x * 128];
    const float v = __int_as_float(p.y);
    a0 += v * __uint_as_float(g.x << 16);
    a1 += v * __uint_as_float(g.x & 0xffff0000u);
    a2 += v * __uint_as_float(g.y << 16);
    a3 += v * __uint_as_float(g.y & 0xffff0000u);
  }

  const int d = chunk * 256 + t * 4;
  const float4 bb = *(const float4*)(b0 + d);
  const bf16_t x0 = (bf16_t)fmaxf(a0 + bb.x, 0.f);
  const bf16_t x1 = (bf16_t)fmaxf(a1 + bb.y, 0.f);
  const bf16_t x2 = (bf16_t)fmaxf(a2 + bb.z, 0.f);
  const bf16_t x3 = (bf16_t)fmaxf(a3 + bb.w, 0.f);
  uint2 pk;
  pk.x = (unsigned int)bf16_bits(x0) | ((unsigned int)bf16_bits(x1) << 16);
  pk.y = (unsigned int)bf16_bits(x2) | ((unsigned int)bf16_bits(x3) << 16);
  ((uint2*)(h + (size_t)row * NH))[chunk * 64 + t] = pk;
}

// ---------------- SpMM D=64: 256-thr blocks = 4 rows; LDS edge staging ----------------
__global__ __launch_bounds__(256) void k_spmm_z(
    const int* __restrict__ rp, const int2* __restrict__ ev,
    const float* __restrict__ HW,
    const float* __restrict__ b1, const float* __restrict__ b2,
    float* __restrict__ out_z, float* __restrict__ out_mu,
    float* __restrict__ out_lv, bf16_t* __restrict__ zb) {
  __shared__ int2 se[512];
  const int rg = blockIdx.x;
  const int tid = threadIdx.x;
  const int r = rg * 4 + (tid >> 6);
  const int t = tid & 63;

  const int base = rp[rg * 4];
  const int cnt = rp[rg * 4 + 4] - base;
  const int scnt = cnt < 512 ? cnt : 512;
  for (int i = tid; i < scnt; i += 256) se[i] = ev[base + i];
  __syncthreads();

  int e = rp[r] - base;
  const int end = rp[r + 1] - base;
  const int se_end = end < 512 ? end : 512;

  float acc = 0.f;
  for (; e + 3 < se_end; e += 4) {
    const int2 p0 = se[e], p1 = se[e + 1], p2 = se[e + 2], p3 = se[e + 3];
    const float s0 = HW[(size_t)p0.x * 64 + t];
    const float s1 = HW[(size_t)p1.x * 64 + t];
    const float s2 = HW[(size_t)p2.x * 64 + t];
    const float s3 = HW[(size_t)p3.x * 64 + t];
    acc += __int_as_float(p0.y) * s0;
    acc += __int_as_float(p1.y) * s1;
    acc += __int_as_float(p2.y) * s2;
    acc += __int_as_float(p3.y) * s3;
  }
  for (; e < se_end; ++e) {
    const int2 p = se[e];
    acc += __int_as_float(p.y) * HW[(size_t)p.x * 64 + t];
  }
  for (; e < end; ++e) {
    const int2 p = ev[base + e];
    acc += __int_as_float(p.y) * HW[(size_t)p.x * 64 + t];
  }

  const float b = (t < ZD) ? b1[t] : b2[t - ZD];
  const float v = fmaxf(acc + b, 0.f);
  if (t < ZD) {
    out_mu[(size_t)r * ZD + t] = v;
    out_z[(size_t)r * ZD + t] = v;
    zb[(size_t)r * ZD + t] = (bf16_t)v;
  } else {
    out_lv[(size_t)r * ZD + (t - ZD)] = v;
  }
}

// ---------------- decoder: out = sigmoid(Z @ Z^T) f32 ----------------
__global__ __launch_bounds__(256) void k_decoder(const bf16_t* __restrict__ Z,
                                                 float* __restrict__ out) {
  __shared__ bf16_t Zr[128 * 32];
  __shared__ bf16_t Zc[128 * 32];
  __shared__ float tile[64][132];
  const int tid = threadIdx.x;
  const int lane = tid & 63, wave = tid >> 6;
  const int wx = wave & 1, wy = wave >> 1;
  const int m0 = blockIdx.y * 128, n0 = blockIdx.x * 128;
  const int q = lane >> 4, ml = lane & 15;
  const int sr = tid >> 2, ss = tid & 3;
  const int sw_lo = sr * 32 + ((ss ^ (sr & 3)) * 8);
  const int sw_hi = sw_lo + 64 * 32;

  *(int4*)(&Zr[sw_lo]) = *((const int4*)(Z + (size_t)(m0 + sr) * ZD) + ss);
  *(int4*)(&Zr[sw_hi]) = *((const int4*)(Z + (size_t)(m0 + sr + 64) * ZD) + ss);
  *(int4*)(&Zc[sw_lo]) = *((const int4*)(Z + (size_t)(n0 + sr) * ZD) + ss);
  *(int4*)(&Zc[sw_hi]) = *((const int4*)(Z + (size_t)(n0 + sr + 64) * ZD) + ss);
  __syncthreads();

  bf16x8 af[4], bfr[4];
  #pragma unroll
  for (int i = 0; i < 4; ++i) {
    int m = wy * 64 + i * 16 + ml;
    af[i] = *(const bf16x8*)(&Zr[m * 32 + ((q ^ (m & 3)) * 8)]);
    int n = wx * 64 + i * 16 + ml;
    bfr[i] = *(const bf16x8*)(&Zc[n * 32 + ((q ^ (n & 3)) * 8)]);
  }

  f32x4 acc[4][4];
  const f32x4 zero = (f32x4){0.f, 0.f, 0.f, 0.f};
  #pragma unroll
  for (int i = 0; i < 4; ++i)
    #pragma unroll
    for (int j = 0; j < 4; ++j)
      acc[i][j] = __builtin_amdgcn_mfma_f32_16x16x32_bf16(af[i], bfr[j], zero, 0, 0, 0);

  #pragma unroll
  for (int i = 0; i < 4; ++i)
    #pragma unroll
    for (int j = 0; j < 4; ++j)
      #pragma unroll
      for (int r = 0; r < 4; ++r)
        acc[i][j][r] = 1.f / (1.f + __expf(-acc[i][j][r]));

  const int g = tid >> 5, c4 = tid & 31;
  #pragma unroll
  for (int half = 0; half < 2; ++half) {
    if (wy == half) {
      #pragma unroll
      for (int i = 0; i < 4; ++i)
        #pragma unroll
        for (int j = 0; j < 4; ++j)
          #pragma unroll
          for (int r = 0; r < 4; ++r)
            tile[i * 16 + q * 4 + r][wx * 64 + j * 16 + ml] = acc[i][j][r];
    }
    __syncthreads();
    float* orow = out + (size_t)(m0 + half * 64) * NN + n0;
    #pragma unroll
    for (int p = 0; p < 8; ++p) {
      const int lr = p * 8 + g;
      f32x4 v = *(const f32x4*)&tile[lr][c4 * 4];
      __builtin_nontemporal_store(v, (f32x4*)(orow + (size_t)lr * NN + c4 * 4));
    }
    __syncthreads();
  }
}

extern "C" void kernel_launch(void* const* d_in, const int* in_sizes, int n_in,
                              void* d_out, int out_size, void* d_ws, size_t ws_size,
                              hipStream_t stream) {
  const float* x        = (const float*)d_in[0];
  const float* adj_vals = (const float*)d_in[1];
  const float* W0       = (const float*)d_in[2];
  const float* b0       = (const float*)d_in[3];
  const float* W1       = (const float*)d_in[4];
  const float* b1       = (const float*)d_in[5];
  const float* W2       = (const float*)d_in[6];
  const float* b2       = (const float*)d_in[7];
  const int* adj_rows   = (const int*)d_in[8];
  const int* adj_cols   = (const int*)d_in[9];

  char* ws = (char*)d_ws;
  bf16_t* XW0b = (bf16_t*)(ws);                  // 8192*512*2   =  8388608
  float*  HW   = (float*)(ws + 8388608);         // 8192*64*4    =  2097152
  bf16_t* h    = (bf16_t*)(ws + 10485760);       // 8192*512*2   =  8388608
  bf16_t* W0t  = (bf16_t*)(ws + 18874368);       // 512*1024*2   =  1048576
  bf16_t* Wct  = (bf16_t*)(ws + 19922944);       // 64*512*2     =    65536
  bf16_t* xb   = (bf16_t*)(ws + 19988480);       // 8192*1024*2  = 16777216
  bf16_t* zb   = (bf16_t*)(ws + 36765696);       // 8192*32*2    =   524288
  int*    rp   = (int*)(ws + 37289984);          // 8193*4       =    32772
  int2*   ev   = (int2*)(ws + 37322768);         // 262144*8     =  2097152  (16-aligned)

  float* out     = (float*)d_out;
  float* out_adj = out;
  float* out_z   = out + (size_t)NN * NN;
  float* out_mu  = out_z + (size_t)NN * ZD;
  float* out_lv  = out_mu + (size_t)NN * ZD;

  // fused prep: cvt + transposes + rowptr + edge pack
  k_prep<<<4929, 256, 0, stream>>>(x, xb, W0, W0t, W1, W2, Wct,
                                   adj_rows, rp, adj_cols, adj_vals, ev);

  // layer 1: XW0b = bf16(x @ W0) ; h = relu(spmm(XW0b) + b0)
  k_gemm_bt_128x128<<<dim3(NH / 128, NN / 128), 256, 0, stream>>>(xb, W0t, XW0b, NN, NH, NF);
  k_spmm_h<<<NN / 4, 512, 0, stream>>>(rp, ev, (const uint2*)XW0b, b0, h);

  // layer 2: HW = h @ [W1|W2] ; mu/logvar = relu(spmm(HW) + b)
  k_gemm_bt_128x64<<<dim3(1, NN / 128), 256, 0, stream>>>(h, Wct, HW, NN, 64, NH);
  k_spmm_z<<<NN / 4, 256, 0, stream>>>(rp, ev, HW, b1, b2, out_z, out_mu, out_lv, zb);

  // decoder
  k_decoder<<<dim3(NN / 128, NN / 128), 256, 0, stream>>>(zb, out_adj);
}

// Round 7
// 377.061 us; speedup vs baseline: 1.1528x; 1.0072x over previous
//
#include <hip/hip_runtime.h>
#include <hip/hip_bf16.h>

typedef __bf16 bf16_t;
typedef __bf16 bf16x8 __attribute__((ext_vector_type(8)));
typedef float f32x4 __attribute__((ext_vector_type(4)));

#define NN 8192
#define EE 262144
#define NF 1024
#define NH 512
#define ZD 32

static __device__ __forceinline__ unsigned short bf16_bits(bf16_t v) {
  union { bf16_t b; unsigned short u; } c;
  c.b = v;
  return c.u;
}

// ---------------- fused prep: cvt x | transpose W0 | transpose W1/W2 | rowptr | edge pack ----------------
// block ranges: [0,4096) cvt, [4096,4608) W0^T, [4608,4640) W12^T, [4640,4673) rowptr, [4673,4929) edge pack
__global__ __launch_bounds__(256) void k_prep(
    const float* __restrict__ x, bf16_t* __restrict__ xb,
    const float* __restrict__ W0, bf16_t* __restrict__ W0t,
    const float* __restrict__ W1, const float* __restrict__ W2, bf16_t* __restrict__ Wct,
    const int* __restrict__ rows, int* __restrict__ rp,
    const int* __restrict__ cols, const float* __restrict__ vals, int2* __restrict__ ev) {
  __shared__ float tile[32][33];
  const int b = blockIdx.x;
  const int tid = threadIdx.x;

  if (b < 4096) {
    // cvt x -> bf16, 8 elems/thread (4096*256*8 == NN*NF exactly)
    const int i = b * 256 + tid;
    const float4 a = ((const float4*)x)[i * 2];
    const float4 c = ((const float4*)x)[i * 2 + 1];
    bf16x8 o;
    o[0] = (bf16_t)a.x; o[1] = (bf16_t)a.y; o[2] = (bf16_t)a.z; o[3] = (bf16_t)a.w;
    o[4] = (bf16_t)c.x; o[5] = (bf16_t)c.y; o[6] = (bf16_t)c.z; o[7] = (bf16_t)c.w;
    ((bf16x8*)xb)[i] = o;
  } else if (b < 4608) {
    // W0 [NF,NH] f32 -> W0t [NH,NF] bf16
    const int bx = b - 4096;
    const int c0 = (bx & 15) * 32, r0 = (bx >> 4) * 32;
    const int tx = tid & 31, ty = tid >> 5;
    #pragma unroll
    for (int i = ty; i < 32; i += 8)
      tile[i][tx] = W0[(size_t)(r0 + i) * NH + (c0 + tx)];
    __syncthreads();
    #pragma unroll
    for (int i = ty; i < 32; i += 8)
      W0t[(size_t)(c0 + i) * NF + (r0 + tx)] = (bf16_t)tile[tx][i];
  } else if (b < 4640) {
    // W1|W2 [NH,ZD] f32 -> Wct [64,NH] bf16
    const int idx = b - 4608;
    const int z = idx & 1, y = idx >> 1;
    const float* in = z ? W2 : W1;
    bf16_t* o = Wct + (size_t)z * ZD * NH;
    const int r0 = y * 32;
    const int tx = tid & 31, ty = tid >> 5;
    #pragma unroll
    for (int i = ty; i < 32; i += 8)
      tile[i][tx] = in[(size_t)(r0 + i) * ZD + tx];
    __syncthreads();
    #pragma unroll
    for (int i = ty; i < 32; i += 8)
      o[(size_t)(i)*NH + (r0 + tx)] = (bf16_t)tile[tx][i];
  } else if (b < 4673) {
    // CSR row_ptr via binary search over sorted rows
    const int r = (b - 4640) * 256 + tid;
    if (r > NN) return;
    if (r == NN) { rp[NN] = EE; return; }
    int lo = 0, hi = EE;
    while (lo < hi) { int mid = (lo + hi) >> 1; if (rows[mid] < r) lo = mid + 1; else hi = mid; }
    rp[r] = lo;
  } else {
    // pack (col, val) -> int2, 4 edges/thread (256 blocks * 256 thr * 4 == EE exactly)
    const int i = ((b - 4673) * 256 + tid) * 4;
    const int4 c4 = *(const int4*)(cols + i);
    const float4 v4 = *(const float4*)(vals + i);
    int4* dst = (int4*)(ev + i);
    dst[0] = make_int4(c4.x, __float_as_int(v4.x), c4.y, __float_as_int(v4.y));
    dst[1] = make_int4(c4.z, __float_as_int(v4.z), c4.w, __float_as_int(v4.w));
  }
}

// ---------------- GEMM1: XW0b[M,N] bf16 = A[M,K] bf16 @ Bt[N,K]^T, 128x128 tile ----------------
__global__ __launch_bounds__(256) void k_gemm_bt_128x128(
    const bf16_t* __restrict__ A, const bf16_t* __restrict__ Bt,
    bf16_t* __restrict__ C, int M, int N, int K) {
  __shared__ bf16_t As[128 * 32];
  __shared__ bf16_t Bs[128 * 32];
  const int tid = threadIdx.x;
  const int lane = tid & 63, wave = tid >> 6;
  const int wx = wave & 1, wy = wave >> 1;
  const int m0 = blockIdx.y * 128, n0 = blockIdx.x * 128;
  const int q = lane >> 4, ml = lane & 15;

  const int sr = tid >> 2, ss = tid & 3;
  const int sw_lo = sr * 32 + ((ss ^ (sr & 3)) * 8);
  const int sw_hi = sw_lo + 64 * 32;

  int a_off[4], b_off[4];
  #pragma unroll
  for (int i = 0; i < 4; ++i) {
    int m = wy * 64 + i * 16 + ml;
    a_off[i] = m * 32 + ((q ^ (m & 3)) * 8);
    int n = wx * 64 + i * 16 + ml;
    b_off[i] = n * 32 + ((q ^ (n & 3)) * 8);
  }

  f32x4 acc[4][4];
  #pragma unroll
  for (int i = 0; i < 4; ++i)
    #pragma unroll
    for (int j = 0; j < 4; ++j)
      acc[i][j] = (f32x4){0.f, 0.f, 0.f, 0.f};

  const bf16_t* ga = A + (size_t)(m0 + sr) * K + ss * 8;
  const bf16_t* gb = Bt + (size_t)(n0 + sr) * K + ss * 8;
  const size_t stride64 = (size_t)64 * K;

  for (int k0 = 0; k0 < K; k0 += 32) {
    int4 va0 = *(const int4*)(ga + k0);
    int4 va1 = *(const int4*)(ga + stride64 + k0);
    int4 vb0 = *(const int4*)(gb + k0);
    int4 vb1 = *(const int4*)(gb + stride64 + k0);
    __syncthreads();
    *(int4*)(&As[sw_lo]) = va0;
    *(int4*)(&As[sw_hi]) = va1;
    *(int4*)(&Bs[sw_lo]) = vb0;
    *(int4*)(&Bs[sw_hi]) = vb1;
    __syncthreads();
    bf16x8 af[4], bfr[4];
    #pragma unroll
    for (int i = 0; i < 4; ++i) af[i] = *(const bf16x8*)(&As[a_off[i]]);
    #pragma unroll
    for (int j = 0; j < 4; ++j) bfr[j] = *(const bf16x8*)(&Bs[b_off[j]]);
    #pragma unroll
    for (int i = 0; i < 4; ++i)
      #pragma unroll
      for (int j = 0; j < 4; ++j)
        acc[i][j] = __builtin_amdgcn_mfma_f32_16x16x32_bf16(af[i], bfr[j], acc[i][j], 0, 0, 0);
  }

  #pragma unroll
  for (int i = 0; i < 4; ++i) {
    const int row = m0 + wy * 64 + i * 16 + q * 4;
    #pragma unroll
    for (int j = 0; j < 4; ++j) {
      const int col = n0 + wx * 64 + j * 16 + ml;
      #pragma unroll
      for (int r = 0; r < 4; ++r)
        C[(size_t)(row + r) * N + col] = (bf16_t)acc[i][j][r];
    }
  }
}

// ---------------- GEMM2: HW f32 = h bf16 @ Wct^T, 64x64 tile (128 blocks -> better CU coverage) ----------------
__global__ __launch_bounds__(256) void k_gemm_bt_64x64(
    const bf16_t* __restrict__ A, const bf16_t* __restrict__ Bt,
    float* __restrict__ C, int M, int N, int K) {
  __shared__ bf16_t As[64 * 32];
  __shared__ bf16_t Bs[64 * 32];
  const int tid = threadIdx.x;
  const int lane = tid & 63, wave = tid >> 6;
  const int m0 = blockIdx.y * 64;
  const int q = lane >> 4, ml = lane & 15;
  const int sr = tid >> 2, ss = tid & 3;           // sr in [0,64)
  const int sw = sr * 32 + ((ss ^ (sr & 3)) * 8);

  const int m = wave * 16 + ml;
  const int a_off = m * 32 + ((q ^ (m & 3)) * 8);
  int b_off[4];
  #pragma unroll
  for (int j = 0; j < 4; ++j) {
    int n = j * 16 + ml;
    b_off[j] = n * 32 + ((q ^ (n & 3)) * 8);
  }

  f32x4 acc[4];
  #pragma unroll
  for (int j = 0; j < 4; ++j) acc[j] = (f32x4){0.f, 0.f, 0.f, 0.f};

  const bf16_t* ga = A + (size_t)(m0 + sr) * K + ss * 8;
  const bf16_t* gb = Bt + (size_t)sr * K + ss * 8;

  for (int k0 = 0; k0 < K; k0 += 32) {
    int4 va = *(const int4*)(ga + k0);
    int4 vb = *(const int4*)(gb + k0);
    __syncthreads();
    *(int4*)(&As[sw]) = va;
    *(int4*)(&Bs[sw]) = vb;
    __syncthreads();
    bf16x8 af = *(const bf16x8*)(&As[a_off]);
    bf16x8 bfr[4];
    #pragma unroll
    for (int j = 0; j < 4; ++j) bfr[j] = *(const bf16x8*)(&Bs[b_off[j]]);
    #pragma unroll
    for (int j = 0; j < 4; ++j)
      acc[j] = __builtin_amdgcn_mfma_f32_16x16x32_bf16(af, bfr[j], acc[j], 0, 0, 0);
  }

  const int row = m0 + wave * 16 + q * 4;
  #pragma unroll
  for (int j = 0; j < 4; ++j) {
    const int col = j * 16 + ml;
    #pragma unroll
    for (int r = 0; r < 4; ++r)
      C[(size_t)(row + r) * N + col] = acc[j][r];
  }
}

// ---------------- SpMM layer1: chunked for L2 residency + LDS edge staging ----------------
// grid = (NN/8)*4; chunk = blockIdx&3 covers 128 cols (2MB table slice). Round-robin
// dispatch pins chunk c to XCDs {c, c+4} -> per-XCD L2 working set 2MB < 4MB.
// 512-thr block = 8 waves = 8 rows x 1 chunk; lane t gathers dword (2 bf16) at
// row*256 + chunk*64 + t. Edges staged once per block into LDS.
__global__ __launch_bounds__(512) void k_spmm_h(
    const int* __restrict__ rp, const int2* __restrict__ ev,
    const unsigned int* __restrict__ XW0b, const float* __restrict__ b0,
    bf16_t* __restrict__ h) {
  __shared__ int2 se[768];
  const int chunk = blockIdx.x & 3;
  const int rg = blockIdx.x >> 2;          // group of 8 rows
  const int tid = threadIdx.x;
  const int wave = tid >> 6, t = tid & 63;
  const int row = rg * 8 + wave;

  const int base = rp[rg * 8];
  const int cnt = rp[rg * 8 + 8] - base;
  const int scnt = cnt < 768 ? cnt : 768;
  for (int i = tid; i < scnt; i += 512) se[i] = ev[base + i];
  __syncthreads();

  int e = rp[row] - base;
  const int end = rp[row + 1] - base;
  const int se_end = end < 768 ? end : 768;
  const unsigned int* tab = XW0b + chunk * 64 + t;   // dword units; row stride 256 dwords

  float a0 = 0.f, a1 = 0.f;
  for (; e + 3 < se_end; e += 4) {
    const int2 p0 = se[e], p1 = se[e + 1], p2 = se[e + 2], p3 = se[e + 3];
    const unsigned int g0 = tab[(size_t)p0.x * 256];
    const unsigned int g1 = tab[(size_t)p1.x * 256];
    const unsigned int g2 = tab[(size_t)p2.x * 256];
    const unsigned int g3 = tab[(size_t)p3.x * 256];
    const float v0 = __int_as_float(p0.y), v1 = __int_as_float(p1.y);
    const float v2 = __int_as_float(p2.y), v3 = __int_as_float(p3.y);
    a0 += v0 * __uint_as_float(g0 << 16);
    a1 += v0 * __uint_as_float(g0 & 0xffff0000u);
    a0 += v1 * __uint_as_float(g1 << 16);
    a1 += v1 * __uint_as_float(g1 & 0xffff0000u);
    a0 += v2 * __uint_as_float(g2 << 16);
    a1 += v2 * __uint_as_float(g2 & 0xffff0000u);
    a0 += v3 * __uint_as_float(g3 << 16);
    a1 += v3 * __uint_as_float(g3 & 0xffff0000u);
  }
  for (; e < se_end; ++e) {
    const int2 p = se[e];
    const unsigned int g = tab[(size_t)p.x * 256];
    const float v = __int_as_float(p.y);
    a0 += v * __uint_as_float(g << 16);
    a1 += v * __uint_as_float(g & 0xffff0000u);
  }
  for (; e < end; ++e) {  // spill path if >768 edges in an 8-row group (not expected)
    const int2 p = ev[base + e];
    const unsigned int g = tab[(size_t)p.x * 256];
    const float v = __int_as_float(p.y);
    a0 += v * __uint_as_float(g << 16);
    a1 += v * __uint_as_float(g & 0xffff0000u);
  }

  const int d = chunk * 128 + t * 2;
  const float2 bb = *(const float2*)(b0 + d);
  const bf16_t x0 = (bf16_t)fmaxf(a0 + bb.x, 0.f);
  const bf16_t x1 = (bf16_t)fmaxf(a1 + bb.y, 0.f);
  const unsigned int pk = (unsigned int)bf16_bits(x0) | ((unsigned int)bf16_bits(x1) << 16);
  *(unsigned int*)(h + (size_t)row * NH + d) = pk;
}

// ---------------- SpMM D=64: 256-thr blocks = 4 rows; LDS edge staging ----------------
__global__ __launch_bounds__(256) void k_spmm_z(
    const int* __restrict__ rp, const int2* __restrict__ ev,
    const float* __restrict__ HW,
    const float* __restrict__ b1, const float* __restrict__ b2,
    float* __restrict__ out_z, float* __restrict__ out_mu,
    float* __restrict__ out_lv, bf16_t* __restrict__ zb) {
  __shared__ int2 se[512];
  const int rg = blockIdx.x;
  const int tid = threadIdx.x;
  const int r = rg * 4 + (tid >> 6);
  const int t = tid & 63;

  const int base = rp[rg * 4];
  const int cnt = rp[rg * 4 + 4] - base;
  const int scnt = cnt < 512 ? cnt : 512;
  for (int i = tid; i < scnt; i += 256) se[i] = ev[base + i];
  __syncthreads();

  int e = rp[r] - base;
  const int end = rp[r + 1] - base;
  const int se_end = end < 512 ? end : 512;

  float acc = 0.f;
  for (; e + 3 < se_end; e += 4) {
    const int2 p0 = se[e], p1 = se[e + 1], p2 = se[e + 2], p3 = se[e + 3];
    const float s0 = HW[(size_t)p0.x * 64 + t];
    const float s1 = HW[(size_t)p1.x * 64 + t];
    const float s2 = HW[(size_t)p2.x * 64 + t];
    const float s3 = HW[(size_t)p3.x * 64 + t];
    acc += __int_as_float(p0.y) * s0;
    acc += __int_as_float(p1.y) * s1;
    acc += __int_as_float(p2.y) * s2;
    acc += __int_as_float(p3.y) * s3;
  }
  for (; e < se_end; ++e) {
    const int2 p = se[e];
    acc += __int_as_float(p.y) * HW[(size_t)p.x * 64 + t];
  }
  for (; e < end; ++e) {
    const int2 p = ev[base + e];
    acc += __int_as_float(p.y) * HW[(size_t)p.x * 64 + t];
  }

  const float b = (t < ZD) ? b1[t] : b2[t - ZD];
  const float v = fmaxf(acc + b, 0.f);
  if (t < ZD) {
    out_mu[(size_t)r * ZD + t] = v;
    out_z[(size_t)r * ZD + t] = v;
    zb[(size_t)r * ZD + t] = (bf16_t)v;
  } else {
    out_lv[(size_t)r * ZD + (t - ZD)] = v;
  }
}

// ---------------- decoder: out = sigmoid(Z @ Z^T) f32 ----------------
// sigmoid via v_rcp (1 trans) instead of full-precision div (~8 ops incl 2 trans):
// at 268M elements the epilogue VALU cost matters. rcp error ~1ulp << bf16 error.
__global__ __launch_bounds__(256) void k_decoder(const bf16_t* __restrict__ Z,
                                                 float* __restrict__ out) {
  __shared__ bf16_t Zr[128 * 32];
  __shared__ bf16_t Zc[128 * 32];
  __shared__ float tile[64][132];
  const int tid = threadIdx.x;
  const int lane = tid & 63, wave = tid >> 6;
  const int wx = wave & 1, wy = wave >> 1;
  const int m0 = blockIdx.y * 128, n0 = blockIdx.x * 128;
  const int q = lane >> 4, ml = lane & 15;
  const int sr = tid >> 2, ss = tid & 3;
  const int sw_lo = sr * 32 + ((ss ^ (sr & 3)) * 8);
  const int sw_hi = sw_lo + 64 * 32;

  *(int4*)(&Zr[sw_lo]) = *((const int4*)(Z + (size_t)(m0 + sr) * ZD) + ss);
  *(int4*)(&Zr[sw_hi]) = *((const int4*)(Z + (size_t)(m0 + sr + 64) * ZD) + ss);
  *(int4*)(&Zc[sw_lo]) = *((const int4*)(Z + (size_t)(n0 + sr) * ZD) + ss);
  *(int4*)(&Zc[sw_hi]) = *((const int4*)(Z + (size_t)(n0 + sr + 64) * ZD) + ss);
  __syncthreads();

  bf16x8 af[4], bfr[4];
  #pragma unroll
  for (int i = 0; i < 4; ++i) {
    int m = wy * 64 + i * 16 + ml;
    af[i] = *(const bf16x8*)(&Zr[m * 32 + ((q ^ (m & 3)) * 8)]);
    int n = wx * 64 + i * 16 + ml;
    bfr[i] = *(const bf16x8*)(&Zc[n * 32 + ((q ^ (n & 3)) * 8)]);
  }

  f32x4 acc[4][4];
  const f32x4 zero = (f32x4){0.f, 0.f, 0.f, 0.f};
  #pragma unroll
  for (int i = 0; i < 4; ++i)
    #pragma unroll
    for (int j = 0; j < 4; ++j)
      acc[i][j] = __builtin_amdgcn_mfma_f32_16x16x32_bf16(af[i], bfr[j], zero, 0, 0, 0);

  #pragma unroll
  for (int i = 0; i < 4; ++i)
    #pragma unroll
    for (int j = 0; j < 4; ++j)
      #pragma unroll
      for (int r = 0; r < 4; ++r)
        acc[i][j][r] = __builtin_amdgcn_rcpf(1.f + __expf(-acc[i][j][r]));

  const int g = tid >> 5, c4 = tid & 31;
  #pragma unroll
  for (int half = 0; half < 2; ++half) {
    if (wy == half) {
      #pragma unroll
      for (int i = 0; i < 4; ++i)
        #pragma unroll
        for (int j = 0; j < 4; ++j)
          #pragma unroll
          for (int r = 0; r < 4; ++r)
            tile[i * 16 + q * 4 + r][wx * 64 + j * 16 + ml] = acc[i][j][r];
    }
    __syncthreads();
    float* orow = out + (size_t)(m0 + half * 64) * NN + n0;
    #pragma unroll
    for (int p = 0; p < 8; ++p) {
      const int lr = p * 8 + g;
      f32x4 v = *(const f32x4*)&tile[lr][c4 * 4];
      __builtin_nontemporal_store(v, (f32x4*)(orow + (size_t)lr * NN + c4 * 4));
    }
    __syncthreads();
  }
}

extern "C" void kernel_launch(void* const* d_in, const int* in_sizes, int n_in,
                              void* d_out, int out_size, void* d_ws, size_t ws_size,
                              hipStream_t stream) {
  const float* x        = (const float*)d_in[0];
  const float* adj_vals = (const float*)d_in[1];
  const float* W0       = (const float*)d_in[2];
  const float* b0       = (const float*)d_in[3];
  const float* W1       = (const float*)d_in[4];
  const float* b1       = (const float*)d_in[5];
  const float* W2       = (const float*)d_in[6];
  const float* b2       = (const float*)d_in[7];
  const int* adj_rows   = (const int*)d_in[8];
  const int* adj_cols   = (const int*)d_in[9];

  char* ws = (char*)d_ws;
  bf16_t* XW0b = (bf16_t*)(ws);                  // 8192*512*2   =  8388608
  float*  HW   = (float*)(ws + 8388608);         // 8192*64*4    =  2097152
  bf16_t* h    = (bf16_t*)(ws + 10485760);       // 8192*512*2   =  8388608
  bf16_t* W0t  = (bf16_t*)(ws + 18874368);       // 512*1024*2   =  1048576
  bf16_t* Wct  = (bf16_t*)(ws + 19922944);       // 64*512*2     =    65536
  bf16_t* xb   = (bf16_t*)(ws + 19988480);       // 8192*1024*2  = 16777216
  bf16_t* zb   = (bf16_t*)(ws + 36765696);       // 8192*32*2    =   524288
  int*    rp   = (int*)(ws + 37289984);          // 8193*4       =    32772
  int2*   ev   = (int2*)(ws + 37322768);         // 262144*8     =  2097152  (16-aligned)

  float* out     = (float*)d_out;
  float* out_adj = out;
  float* out_z   = out + (size_t)NN * NN;
  float* out_mu  = out_z + (size_t)NN * ZD;
  float* out_lv  = out_mu + (size_t)NN * ZD;

  // fused prep: cvt + transposes + rowptr + edge pack
  k_prep<<<4929, 256, 0, stream>>>(x, xb, W0, W0t, W1, W2, Wct,
                                   adj_rows, rp, adj_cols, adj_vals, ev);

  // layer 1: XW0b = bf16(x @ W0) ; h = relu(spmm(XW0b) + b0)
  k_gemm_bt_128x128<<<dim3(NH / 128, NN / 128), 256, 0, stream>>>(xb, W0t, XW0b, NN, NH, NF);
  k_spmm_h<<<(NN / 8) * 4, 512, 0, stream>>>(rp, ev, (const unsigned int*)XW0b, b0, h);

  // layer 2: HW = h @ [W1|W2] ; mu/logvar = relu(spmm(HW) + b)
  k_gemm_bt_64x64<<<dim3(1, NN / 64), 256, 0, stream>>>(h, Wct, HW, NN, 64, NH);
  k_spmm_z<<<NN / 4, 256, 0, stream>>>(rp, ev, HW, b1, b2, out_z, out_mu, out_lv, zb);

  // decoder
  k_decoder<<<dim3(NN / 128, NN / 128), 256, 0, stream>>>(zb, out_adj);
}